// Round 16
// baseline (202.786 us; speedup 1.0000x reference)
//
#include <hip/hip_runtime.h>
#include <hip/hip_bf16.h>

#define SEQ  256
#define DIM  20
#define NCLS 5

typedef short  bf16x8 __attribute__((ext_vector_type(8)));
typedef float  f32x4  __attribute__((ext_vector_type(4)));
typedef float  v2f    __attribute__((ext_vector_type(2)));

__device__ __forceinline__ v2f fast_tanh2(v2f x) {
    // tanh(x) = 1 - 2/(exp(2x)+1); packed mul/add/fma, scalar exp/rcp
    v2f xs = x * 2.8853900817779268f;
    v2f e;
    e.x = __builtin_amdgcn_exp2f(xs.x);
    e.y = __builtin_amdgcn_exp2f(xs.y);
    v2f d = e + 1.0f;
    v2f r;
    r.x = __builtin_amdgcn_rcpf(d.x);
    r.y = __builtin_amdgcn_rcpf(d.y);
    return __builtin_elementwise_fma((v2f)(-2.0f), r, (v2f)(1.0f));
}

__device__ __forceinline__ int cvt_pk_bf16(float lo, float hi) {
    int r;
    asm("v_cvt_pk_bf16_f32 %0, %1, %2" : "=v"(r) : "v"(lo), "v"(hi));
    return r;
}

// v_permlane32_swap_b32 a, b  (S1 semantics, established by r8/r9 A-B result):
//   a' : lanes 0-31 = a(0-31),  lanes 32-63 = b(0-31)
//   b' : lanes 0-31 = a(32-63), lanes 32-63 = b(32-63)
__device__ __forceinline__ void pl32swap(int &a, int &b) {
    asm("v_permlane32_swap_b32 %0, %1" : "+v"(a), "+v"(b));
}

// Recurrent-contraction column permutation (A-column kappa holds unit
// perm(kappa)): [0-3]->u0-3, [4-7]->u8-11, [8-11]->u4-7, [12-15]->u12-15,
// [16-19]->u16-19. Whole h-exchange = 2 permlane32_swap, zero DS.
__device__ __forceinline__ int permk(int k) {
    return (k >= 4 && k < 8) ? k + 4 : (k >= 8 && k < 12) ? k - 4 : k;
}

union I4B { int i[4]; bf16x8 f; };

// One wave = 16 batch rows. r12 structure with the pipeline PINNED:
// the depth-2 stage loads (emb gathers) and depth-2 token loads are VOLATILE
// -> the compiler cannot sink/rematerialize them to their uses (r12's
// collapse, proven by VGPR=48), but the s_waitcnt before each use remains
// compiler-inserted and correct. No inline-asm loads (r13-r15 fault mode).
// Steady state per iter s:
//   issue (volatile): gather emb row of e(s+3) via tokG=x[s+3] (2-iter-old),
//                     token x[s+5]
//   h-MFMA (C = aePre, ready), tanh/cvt/2x permlane-swap -> Bh
//   convert stage A (= e(s+1), loads 2 iters old) -> Be; e-MFMA -> aePre
__global__ __launch_bounds__(256, 1)
void rnn_mfma(const int* __restrict__ x,
              const float* __restrict__ emb,
              const float* __restrict__ W_ih,
              const float* __restrict__ W_hh,
              const float* __restrict__ W_cls,
              const float* __restrict__ b_cls,
              float* __restrict__ out, int B)
{
    const int gtid = blockIdx.x * blockDim.x + threadIdx.x;
    const int wave = gtid >> 6;
    const int lane = (int)(threadIdx.x & 63);
    const int c = lane & 15;      // batch column of the tile
    const int q = lane >> 4;      // quadrant
    const int row0 = wave * 16;
    if (row0 >= B) return;

    // ---- A fragments: lane holds A[row=c][k=8q+j], zero outside bounds.
    auto loadA = [&](const float* M, int U0, int ROWS, bool pk) {
        bf16x8 f;
        const int uu = U0 + c;
        const int ur = uu < ROWS ? uu : 0;
#pragma unroll
        for (int j = 0; j < 8; ++j) {
            const int kk = 8 * q + j;
            const int kp = pk ? permk(kk) : kk;
            const int kr = kp < DIM ? kp : 0;
            float v = M[ur * DIM + kr];
            v = (uu < ROWS && kk < DIM) ? v : 0.0f;
            __hip_bfloat16 hb = __float2bfloat16(v);
            f[j] = *reinterpret_cast<short*>(&hb);
        }
        return f;
    };
    const bf16x8 A0h = loadA(W_hh,  0, DIM,  true);   // units 0-15,  W_hh
    const bf16x8 A0e = loadA(W_ih,  0, DIM,  false);  // units 0-15,  W_ih
    const bf16x8 A1h = loadA(W_hh, 16, DIM,  true);   // units 16-19
    const bf16x8 A1e = loadA(W_ih, 16, DIM,  false);
    const bf16x8 Acl = loadA(W_cls, 0, NCLS, true);   // classes 0-4

    float bias[4];
#pragma unroll
    for (int j = 0; j < 4; ++j) {
        const int idx = 4 * q + j;
        bias[j] = (idx < NCLS) ? b_cls[idx] : 0.0f;
    }

    const int eoff0 = (q == 0) ? 0 : (q == 1) ? 8 : 16;   // e element offsets,
    const int eoff1 = (q == 0) ? 4 : (q == 1) ? 12 : 16;  // clamped in-bounds

    const int* xp = x + (size_t)(row0 + c) * SEQ;
    const f32x4 zf = {0.0f, 0.0f, 0.0f, 0.0f};

    // ---- prologue (plain loads; they complete before the loop) -------------
    I4B Bh; Bh.i[0] = Bh.i[1] = Bh.i[2] = Bh.i[3] = 0;
    I4B Be;
    const int tk0 = xp[0];
    const int tk1 = xp[1];
    const int tk2 = xp[2];
    {   // e(0) -> Be -> aePre for step 0
        const f32x4 lo = *(const f32x4*)(emb + (size_t)tk0 * DIM + eoff0);
        const f32x4 hi = *(const f32x4*)(emb + (size_t)tk0 * DIM + eoff1);
        const bool nz = (tk0 != 0);    // padding_idx = 0
        Be.i[0] = nz ? cvt_pk_bf16(lo[0], lo[1]) : 0;
        Be.i[1] = nz ? cvt_pk_bf16(lo[2], lo[3]) : 0;
        Be.i[2] = nz ? cvt_pk_bf16(hi[0], hi[1]) : 0;
        Be.i[3] = nz ? cvt_pk_bf16(hi[2], hi[3]) : 0;
    }
    f32x4 aePre0 = __builtin_amdgcn_mfma_f32_16x16x32_bf16(A0e, Be.f, zf, 0, 0, 0);
    f32x4 aePre1 = __builtin_amdgcn_mfma_f32_16x16x32_bf16(A1e, Be.f, zf, 0, 0, 0);

    // stage A = e(1), stage B = e(2); token pipeline: tokG = x[3], tokG2 = x[4]
    f32x4 loA, hiA, loB, hiB;
    bool nzA, nzB;
    loA = *(volatile const f32x4*)(emb + (size_t)tk1 * DIM + eoff0);
    hiA = *(volatile const f32x4*)(emb + (size_t)tk1 * DIM + eoff1);
    nzA = (tk1 != 0);
    loB = *(volatile const f32x4*)(emb + (size_t)tk2 * DIM + eoff0);
    hiB = *(volatile const f32x4*)(emb + (size_t)tk2 * DIM + eoff1);
    nzB = (tk2 != 0);
    int tokG  = xp[3];
    int tokG2 = xp[4];

    // ---- main loop ---------------------------------------------------------
#pragma unroll 2
    for (int s = 0; s < SEQ; ++s) {
        // issue (volatile, pinned here): gather e(s+3) via tokG = x[s+3],
        // and token x[s+5] (2 iterations of cover each)
        const f32x4 loC = *(volatile const f32x4*)(emb + (size_t)tokG * DIM + eoff0);
        const f32x4 hiC = *(volatile const f32x4*)(emb + (size_t)tokG * DIM + eoff1);
        const bool nzC = (tokG != 0);
        const int i5 = (s + 5 < SEQ) ? (s + 5) : (SEQ - 1);
        const int tokNew = *(volatile const int*)(xp + i5);

        // h-MFMA chain (aePre is a ready C operand)
        const f32x4 acc0 = __builtin_amdgcn_mfma_f32_16x16x32_bf16(A0h, Bh.f, aePre0, 0, 0, 0);
        const f32x4 acc1 = __builtin_amdgcn_mfma_f32_16x16x32_bf16(A1h, Bh.f, aePre1, 0, 0, 0);

        const v2f p0 = fast_tanh2((v2f){acc0[0], acc0[1]});
        const v2f p1 = fast_tanh2((v2f){acc0[2], acc0[3]});
        const v2f p2 = fast_tanh2((v2f){acc1[0], acc1[1]});
        const v2f p3 = fast_tanh2((v2f){acc1[2], acc1[3]});
        int w0  = cvt_pk_bf16(p0.x, p0.y);
        int w1  = cvt_pk_bf16(p1.x, p1.y);
        int tp0 = cvt_pk_bf16(p2.x, p2.y);
        int tp1 = cvt_pk_bf16(p3.x, p3.y);
        pl32swap(w0, tp0);   // w' = {w_low, t_low}; t' = {w_high, t_high}
        pl32swap(w1, tp1);
        Bh.i[0] = w0;
        Bh.i[1] = w1;
        Bh.i[2] = tp0;
        Bh.i[3] = tp1;

        // convert stage A = e(s+1): loads issued 2 iterations ago
        Be.i[0] = nzA ? cvt_pk_bf16(loA[0], loA[1]) : 0;
        Be.i[1] = nzA ? cvt_pk_bf16(loA[2], loA[3]) : 0;
        Be.i[2] = nzA ? cvt_pk_bf16(hiA[0], hiA[1]) : 0;
        Be.i[3] = nzA ? cvt_pk_bf16(hiA[2], hiA[3]) : 0;

        // e-MFMAs for step s+1 (a full iteration of latency cover)
        aePre0 = __builtin_amdgcn_mfma_f32_16x16x32_bf16(A0e, Be.f, zf, 0, 0, 0);
        aePre1 = __builtin_amdgcn_mfma_f32_16x16x32_bf16(A1e, Be.f, zf, 0, 0, 0);

        // rotate pipeline stages (renamed by the unroll)
        loA = loB; hiA = hiB; nzA = nzB;
        loB = loC; hiB = hiC; nzB = nzC;
        tokG = tokG2; tokG2 = tokNew;
    }

    // ---- classifier: one MFMA (classes in rows 0-4; k-cols >= 20 are zero)
    const f32x4 y = __builtin_amdgcn_mfma_f32_16x16x32_bf16(Acl, Bh.f, zf, 0, 0, 0);
    float* orow = out + (size_t)(row0 + c) * NCLS;
    if (q == 0) {          // rows 0-3 = classes 0-3 for batch row c
        orow[0] = y[0] + bias[0];
        orow[1] = y[1] + bias[1];
        orow[2] = y[2] + bias[2];
        orow[3] = y[3] + bias[3];
    } else if (q == 1) {   // row 4 = class 4
        orow[4] = y[0] + bias[0];
    }
}

extern "C" void kernel_launch(void* const* d_in, const int* in_sizes, int n_in,
                              void* d_out, int out_size, void* d_ws, size_t ws_size,
                              hipStream_t stream) {
    const int*   x     = (const int*)d_in[0];
    const float* emb   = (const float*)d_in[1];
    const float* W_ih  = (const float*)d_in[2];
    const float* W_hh  = (const float*)d_in[3];
    const float* W_cls = (const float*)d_in[4];
    const float* b_cls = (const float*)d_in[5];
    float* out = (float*)d_out;

    const int B = in_sizes[0] / SEQ;            // 16384
    const int threads = B * 4;                   // 64 lanes per 16 rows
    const int block = 256;
    const int grid = (threads + block - 1) / block;   // 1024 waves total
    rnn_mfma<<<grid, block, 0, stream>>>(x, emb, W_ih, W_hh, W_cls, b_cls, out, B);
}

// Round 17
// 74.736 us; speedup vs baseline: 2.7134x; 2.7134x over previous
//
#include <hip/hip_runtime.h>
#include <hip/hip_bf16.h>

#define SEQ  256
#define DIM  20
#define NCLS 5

typedef short  bf16x8 __attribute__((ext_vector_type(8)));
typedef float  f32x4  __attribute__((ext_vector_type(4)));
typedef float  v2f    __attribute__((ext_vector_type(2)));

__device__ __forceinline__ v2f fast_tanh2(v2f x) {
    // tanh(x) = 1 - 2/(exp(2x)+1); packed mul/add/fma, scalar exp/rcp
    v2f xs = x * 2.8853900817779268f;
    v2f e;
    e.x = __builtin_amdgcn_exp2f(xs.x);
    e.y = __builtin_amdgcn_exp2f(xs.y);
    v2f d = e + 1.0f;
    v2f r;
    r.x = __builtin_amdgcn_rcpf(d.x);
    r.y = __builtin_amdgcn_rcpf(d.y);
    return __builtin_elementwise_fma((v2f)(-2.0f), r, (v2f)(1.0f));
}

__device__ __forceinline__ int cvt_pk_bf16(float lo, float hi) {
    int r;
    asm("v_cvt_pk_bf16_f32 %0, %1, %2" : "=v"(r) : "v"(lo), "v"(hi));
    return r;
}

// v_permlane32_swap_b32 a, b  (S1 semantics, established by r8/r9 A-B result):
//   a' : lanes 0-31 = a(0-31),  lanes 32-63 = b(0-31)
//   b' : lanes 0-31 = a(32-63), lanes 32-63 = b(32-63)
__device__ __forceinline__ void pl32swap(int &a, int &b) {
    asm("v_permlane32_swap_b32 %0, %1" : "+v"(a), "+v"(b));
}

// Recurrent-contraction column permutation (A-column kappa holds unit
// perm(kappa)): [0-3]->u0-3, [4-7]->u8-11, [8-11]->u4-7, [12-15]->u12-15,
// [16-19]->u16-19. Whole h-exchange = 2 permlane32_swap, zero DS.
__device__ __forceinline__ int permk(int k) {
    return (k >= 4 && k < 8) ? k + 4 : (k >= 8 && k < 12) ? k - 4 : k;
}

union I4B { int i[4]; bf16x8 f; };

// One wave = 16 batch rows. r12 structure (plain loads, depth-2 token +
// depth-2 gather pipeline) with the scheduler's occupancy target PINNED to
// 1 wave/EU via amdgpu_waves_per_eu(1,1): the machine scheduler no longer
// sinks prefetch loads to crush register pressure for an occupancy this
// grid can never reach (1024 waves = 1 wave/SIMD structurally). unroll 4
// gives a 4-step single-BB scheduling region for in-block load hoisting.
__global__ __launch_bounds__(256)
__attribute__((amdgpu_waves_per_eu(1, 1)))
void rnn_mfma(const int* __restrict__ x,
              const float* __restrict__ emb,
              const float* __restrict__ W_ih,
              const float* __restrict__ W_hh,
              const float* __restrict__ W_cls,
              const float* __restrict__ b_cls,
              float* __restrict__ out, int B)
{
    const int gtid = blockIdx.x * blockDim.x + threadIdx.x;
    const int wave = gtid >> 6;
    const int lane = (int)(threadIdx.x & 63);
    const int c = lane & 15;      // batch column of the tile
    const int q = lane >> 4;      // quadrant
    const int row0 = wave * 16;
    if (row0 >= B) return;

    // ---- A fragments: lane holds A[row=c][k=8q+j], zero outside bounds.
    auto loadA = [&](const float* M, int U0, int ROWS, bool pk) {
        bf16x8 f;
        const int uu = U0 + c;
        const int ur = uu < ROWS ? uu : 0;
#pragma unroll
        for (int j = 0; j < 8; ++j) {
            const int kk = 8 * q + j;
            const int kp = pk ? permk(kk) : kk;
            const int kr = kp < DIM ? kp : 0;
            float v = M[ur * DIM + kr];
            v = (uu < ROWS && kk < DIM) ? v : 0.0f;
            __hip_bfloat16 hb = __float2bfloat16(v);
            f[j] = *reinterpret_cast<short*>(&hb);
        }
        return f;
    };
    const bf16x8 A0h = loadA(W_hh,  0, DIM,  true);   // units 0-15,  W_hh
    const bf16x8 A0e = loadA(W_ih,  0, DIM,  false);  // units 0-15,  W_ih
    const bf16x8 A1h = loadA(W_hh, 16, DIM,  true);   // units 16-19
    const bf16x8 A1e = loadA(W_ih, 16, DIM,  false);
    const bf16x8 Acl = loadA(W_cls, 0, NCLS, true);   // classes 0-4

    float bias[4];
#pragma unroll
    for (int j = 0; j < 4; ++j) {
        const int idx = 4 * q + j;
        bias[j] = (idx < NCLS) ? b_cls[idx] : 0.0f;
    }

    const int eoff0 = (q == 0) ? 0 : (q == 1) ? 8 : 16;   // e element offsets,
    const int eoff1 = (q == 0) ? 4 : (q == 1) ? 12 : 16;  // clamped in-bounds

    const int* xp = x + (size_t)(row0 + c) * SEQ;
    const f32x4 zf = {0.0f, 0.0f, 0.0f, 0.0f};

    // ---- prologue ----------------------------------------------------------
    I4B Bh; Bh.i[0] = Bh.i[1] = Bh.i[2] = Bh.i[3] = 0;
    I4B Be;
    const int tk0 = xp[0];
    const int tk1 = xp[1];
    const int tk2 = xp[2];
    {   // e(0) -> Be -> aePre for step 0
        const f32x4 lo = *(const f32x4*)(emb + (size_t)tk0 * DIM + eoff0);
        const f32x4 hi = *(const f32x4*)(emb + (size_t)tk0 * DIM + eoff1);
        const bool nz = (tk0 != 0);    // padding_idx = 0
        Be.i[0] = nz ? cvt_pk_bf16(lo[0], lo[1]) : 0;
        Be.i[1] = nz ? cvt_pk_bf16(lo[2], lo[3]) : 0;
        Be.i[2] = nz ? cvt_pk_bf16(hi[0], hi[1]) : 0;
        Be.i[3] = nz ? cvt_pk_bf16(hi[2], hi[3]) : 0;
    }
    f32x4 aePre0 = __builtin_amdgcn_mfma_f32_16x16x32_bf16(A0e, Be.f, zf, 0, 0, 0);
    f32x4 aePre1 = __builtin_amdgcn_mfma_f32_16x16x32_bf16(A1e, Be.f, zf, 0, 0, 0);

    // stage A = e(1), stage B = e(2); token pipeline: tokG = x[3], tokG2 = x[4]
    f32x4 loA, hiA, loB, hiB;
    bool nzA, nzB;
    loA = *(const f32x4*)(emb + (size_t)tk1 * DIM + eoff0);
    hiA = *(const f32x4*)(emb + (size_t)tk1 * DIM + eoff1);
    nzA = (tk1 != 0);
    loB = *(const f32x4*)(emb + (size_t)tk2 * DIM + eoff0);
    hiB = *(const f32x4*)(emb + (size_t)tk2 * DIM + eoff1);
    nzB = (tk2 != 0);
    int tokG  = xp[3];
    int tokG2 = xp[4];

    // ---- main loop ---------------------------------------------------------
#pragma unroll 4
    for (int s = 0; s < SEQ; ++s) {
        // issue: gather e(s+3) via tokG = x[s+3] (2-iter-old token),
        // and token x[s+5] (consumed 2 iterations from now)
        const f32x4 loC = *(const f32x4*)(emb + (size_t)tokG * DIM + eoff0);
        const f32x4 hiC = *(const f32x4*)(emb + (size_t)tokG * DIM + eoff1);
        const bool nzC = (tokG != 0);
        const int i5 = (s + 5 < SEQ) ? (s + 5) : (SEQ - 1);
        const int tokNew = xp[i5];

        // h-MFMA chain (aePre is a ready C operand)
        const f32x4 acc0 = __builtin_amdgcn_mfma_f32_16x16x32_bf16(A0h, Bh.f, aePre0, 0, 0, 0);
        const f32x4 acc1 = __builtin_amdgcn_mfma_f32_16x16x32_bf16(A1h, Bh.f, aePre1, 0, 0, 0);

        const v2f p0 = fast_tanh2((v2f){acc0[0], acc0[1]});
        const v2f p1 = fast_tanh2((v2f){acc0[2], acc0[3]});
        const v2f p2 = fast_tanh2((v2f){acc1[0], acc1[1]});
        const v2f p3 = fast_tanh2((v2f){acc1[2], acc1[3]});
        int w0  = cvt_pk_bf16(p0.x, p0.y);
        int w1  = cvt_pk_bf16(p1.x, p1.y);
        int tp0 = cvt_pk_bf16(p2.x, p2.y);
        int tp1 = cvt_pk_bf16(p3.x, p3.y);
        pl32swap(w0, tp0);   // w' = {w_low, t_low}; t' = {w_high, t_high}
        pl32swap(w1, tp1);
        Bh.i[0] = w0;
        Bh.i[1] = w1;
        Bh.i[2] = tp0;
        Bh.i[3] = tp1;

        // convert stage A = e(s+1): loads issued 2 iterations ago
        Be.i[0] = nzA ? cvt_pk_bf16(loA[0], loA[1]) : 0;
        Be.i[1] = nzA ? cvt_pk_bf16(loA[2], loA[3]) : 0;
        Be.i[2] = nzA ? cvt_pk_bf16(hiA[0], hiA[1]) : 0;
        Be.i[3] = nzA ? cvt_pk_bf16(hiA[2], hiA[3]) : 0;

        // e-MFMAs for step s+1 (a full iteration of latency cover)
        aePre0 = __builtin_amdgcn_mfma_f32_16x16x32_bf16(A0e, Be.f, zf, 0, 0, 0);
        aePre1 = __builtin_amdgcn_mfma_f32_16x16x32_bf16(A1e, Be.f, zf, 0, 0, 0);

        // rotate pipeline stages (renamed by the unroll)
        loA = loB; hiA = hiB; nzA = nzB;
        loB = loC; hiB = hiC; nzB = nzC;
        tokG = tokG2; tokG2 = tokNew;
    }

    // ---- classifier: one MFMA (classes in rows 0-4; k-cols >= 20 are zero)
    const f32x4 y = __builtin_amdgcn_mfma_f32_16x16x32_bf16(Acl, Bh.f, zf, 0, 0, 0);
    float* orow = out + (size_t)(row0 + c) * NCLS;
    if (q == 0) {          // rows 0-3 = classes 0-3 for batch row c
        orow[0] = y[0] + bias[0];
        orow[1] = y[1] + bias[1];
        orow[2] = y[2] + bias[2];
        orow[3] = y[3] + bias[3];
    } else if (q == 1) {   // row 4 = class 4
        orow[4] = y[0] + bias[0];
    }
}

extern "C" void kernel_launch(void* const* d_in, const int* in_sizes, int n_in,
                              void* d_out, int out_size, void* d_ws, size_t ws_size,
                              hipStream_t stream) {
    const int*   x     = (const int*)d_in[0];
    const float* emb   = (const float*)d_in[1];
    const float* W_ih  = (const float*)d_in[2];
    const float* W_hh  = (const float*)d_in[3];
    const float* W_cls = (const float*)d_in[4];
    const float* b_cls = (const float*)d_in[5];
    float* out = (float*)d_out;

    const int B = in_sizes[0] / SEQ;            // 16384
    const int threads = B * 4;                   // 64 lanes per 16 rows
    const int block = 256;
    const int grid = (threads + block - 1) / block;   // 1024 waves total
    rnn_mfma<<<grid, block, 0, stream>>>(x, emb, W_ih, W_hh, W_cls, b_cls, out, B);
}